// Round 3
// baseline (25.133 us; speedup 1.0000x reference)
//
#include <hip/hip_runtime.h>
#include <hip/hip_bf16.h>

using f32x4  = __attribute__((ext_vector_type(4))) float;
using bf16x8 = __attribute__((ext_vector_type(8))) short;

constexpr int   G_NUM = 256;
constexpr int   NAUG  = 256;
constexpr int   NORIG = 512;
constexpr int   DIM   = 128;
constexpr float INV_T = 10.0f;

// round-to-nearest-even f32 -> bf16 bits
__device__ __forceinline__ short f32_to_bf16_bits(float x) {
    unsigned u = __float_as_uint(x);
    u += 0x7fffu + ((u >> 16) & 1u);
    return (short)(u >> 16);
}

// 512 blocks = 2 per graph (each owns 128 student rows). 512 threads = 8 waves.
// Deferred normalization: raw bf16 operands into MFMA, per-row/col rsqrt scales
// applied to the f32 scores. Breaks the load->shfl->scale->cvt serial chain.
__global__ __launch_bounds__(512, 4) void nlcl_main(
    const float* __restrict__ student,
    const float* __restrict__ teacher,
    const int*   __restrict__ kept,
    float*       __restrict__ block_sums)
{
    __shared__ short t_lds[NAUG * DIM];   // [256 rows][128 bf16], XOR-swizzled, 64KB
    __shared__ float rt_lds[NAUG];        // rsqrt(sumsq) per teacher tile row
    __shared__ float rs_lds[128];         // rsqrt(sumsq)*10 per student row (this block)
    __shared__ float red[8];

    const int bid = blockIdx.x;
    // XCD-bijective swizzle (512 = 8 XCDs x 64): logical pairs (2g,2g+1) same XCD
    const int logical = (bid & 7) * 64 + (bid >> 3);
    const int g    = logical >> 1;
    const int half = logical & 1;

    const int tid  = threadIdx.x;
    const int lane = tid & 63;
    const int wave = tid >> 6;        // 0..7
    const int rbase = half * 128;     // this block's student-row window

    const float* s_base = student + (size_t)g * NAUG * DIM;
    const float* t_base = teacher + (size_t)g * NORIG * DIM;
    const int*   k_base = kept + g * NAUG;

    const int ccol  = lane & 15;      // frag row select / score col within tile
    const int cquad = lane >> 4;      // 0..3, k-subchunk select

    const int hw = tid >> 5;          // 0..15 (half-wave id) -> teacher tile row group
    const int hl = tid & 31;          // lane within half-wave -> 16B slot in row

    // ---- issue idx loads (head of longest chain) ----
    int idxv[16];
    #pragma unroll
    for (int it = 0; it < 16; ++it) idxv[it] = k_base[it * 16 + hw];

    // ---- issue student loads ----
    const int srow = rbase + wave * 16 + ccol;
    const float* rp = s_base + srow * DIM;
    float4 sv[8];
    #pragma unroll
    for (int kc = 0; kc < 4; ++kc) {
        sv[kc * 2]     = *reinterpret_cast<const float4*>(rp + kc * 32 + cquad * 8);
        sv[kc * 2 + 1] = *reinterpret_cast<const float4*>(rp + kc * 32 + cquad * 8 + 4);
    }

    // ---- issue gather chunks 0,1 (4 rows each); waits only on idx ----
    float4 gv0[4], gv1[4];
    #pragma unroll
    for (int i = 0; i < 4; ++i)
        gv0[i] = *reinterpret_cast<const float4*>(t_base + (size_t)idxv[i] * DIM + hl * 4);
    #pragma unroll
    for (int i = 0; i < 4; ++i)
        gv1[i] = *reinterpret_cast<const float4*>(t_base + (size_t)idxv[4 + i] * DIM + hl * 4);

    // ---- student: raw bf16 frags + sumsq (gathers in flight) ----
    bf16x8 afrag[4];
    {
        float ss = 0.f;
        #pragma unroll
        for (int kc = 0; kc < 4; ++kc) {
            const float4 a = sv[kc * 2], b = sv[kc * 2 + 1];
            afrag[kc][0] = f32_to_bf16_bits(a.x); afrag[kc][1] = f32_to_bf16_bits(a.y);
            afrag[kc][2] = f32_to_bf16_bits(a.z); afrag[kc][3] = f32_to_bf16_bits(a.w);
            afrag[kc][4] = f32_to_bf16_bits(b.x); afrag[kc][5] = f32_to_bf16_bits(b.y);
            afrag[kc][6] = f32_to_bf16_bits(b.z); afrag[kc][7] = f32_to_bf16_bits(b.w);
            ss += a.x * a.x + a.y * a.y + a.z * a.z + a.w * a.w;
            ss += b.x * b.x + b.y * b.y + b.z * b.z + b.w * b.w;
        }
        ss += __shfl_xor(ss, 16);
        ss += __shfl_xor(ss, 32);
        if (cquad == 0)
            rs_lds[wave * 16 + ccol] = rsqrtf(fmaxf(ss, 1e-24f)) * INV_T;
    }

    // ---- gather pipeline: process chunk c while c+1 in flight ----
    char* tl = reinterpret_cast<char*>(t_lds);
    #pragma unroll
    for (int c = 0; c < 4; ++c) {
        float4 cur[4];
        #pragma unroll
        for (int i = 0; i < 4; ++i) cur[i] = (c & 1) ? gv1[i] : gv0[i];
        // issue chunk c+2 into the buffer we just consumed
        if (c < 2) {
            #pragma unroll
            for (int i = 0; i < 4; ++i) {
                float4 nxt = *reinterpret_cast<const float4*>(
                    t_base + (size_t)idxv[(c + 2) * 4 + i] * DIM + hl * 4);
                if (c & 1) gv1[i] = nxt; else gv0[i] = nxt;
            }
        }
        #pragma unroll
        for (int i = 0; i < 4; ++i) {
            const int it = c * 4 + i;
            const int j  = it * 16 + hw;          // teacher tile row
            const float4 v = cur[i];
            // data path: cvt + swizzled LDS write (independent of shfl chain)
            short4 o;
            o.x = f32_to_bf16_bits(v.x); o.y = f32_to_bf16_bits(v.y);
            o.z = f32_to_bf16_bits(v.z); o.w = f32_to_bf16_bits(v.w);
            const int byte = j * 256 + ((hl * 8) ^ ((j & 7) << 4));
            *reinterpret_cast<short4*>(tl + byte) = o;
            // norm path: scalar sumsq reduce
            float ss = v.x * v.x + v.y * v.y + v.z * v.z + v.w * v.w;
            ss += __shfl_xor(ss, 1);
            ss += __shfl_xor(ss, 2);
            ss += __shfl_xor(ss, 4);
            ss += __shfl_xor(ss, 8);
            ss += __shfl_xor(ss, 16);
            if (hl == 0)
                rt_lds[j] = rsqrtf(fmaxf(ss, 1e-24f));
        }
    }
    __syncthreads();

    // ---- MFMA + softmax-sum + diagonal ----
    float sumexp[4] = {0.f, 0.f, 0.f, 0.f};
    float diagsum = 0.f;
    const char* tlc = reinterpret_cast<const char*>(t_lds);
    float rs[4];
    #pragma unroll
    for (int reg = 0; reg < 4; ++reg)
        rs[reg] = rs_lds[wave * 16 + cquad * 4 + reg];

    for (int ct = 0; ct < 16; ++ct) {
        f32x4 acc = {0.f, 0.f, 0.f, 0.f};
        const int j = ct * 16 + ccol;             // teacher row = score col
        const float rt = rt_lds[j];
        #pragma unroll
        for (int kc = 0; kc < 4; ++kc) {
            const int byte = j * 256 + (((kc * 64) + (cquad * 16)) ^ ((j & 7) << 4));
            const bf16x8 b = *reinterpret_cast<const bf16x8*>(tlc + byte);
            acc = __builtin_amdgcn_mfma_f32_16x16x32_bf16(afrag[kc], b, acc, 0, 0, 0);
        }
        #pragma unroll
        for (int reg = 0; reg < 4; ++reg) {
            const int row = rbase + wave * 16 + cquad * 4 + reg;
            const float l = acc[reg] * rs[reg] * rt;   // rs carries the *10
            sumexp[reg] += __expf(l);
            if (j == row) diagsum += l;
        }
    }

    // ---- reduce: sum_i log(sumexp_i) - sum_i diag_i ----
    float ce = 0.f;
    #pragma unroll
    for (int reg = 0; reg < 4; ++reg) {
        float s = sumexp[reg];
        s += __shfl_xor(s, 1);
        s += __shfl_xor(s, 2);
        s += __shfl_xor(s, 4);
        s += __shfl_xor(s, 8);
        if (ccol == 0) ce += __logf(s);           // one lane per (cquad,reg) row
    }
    ce -= diagsum;
    ce += __shfl_xor(ce, 1);
    ce += __shfl_xor(ce, 2);
    ce += __shfl_xor(ce, 4);
    ce += __shfl_xor(ce, 8);
    ce += __shfl_xor(ce, 16);
    ce += __shfl_xor(ce, 32);

    if (lane == 0) red[wave] = ce;
    __syncthreads();
    if (tid == 0) {
        float t = 0.f;
        #pragma unroll
        for (int w = 0; w < 8; ++w) t += red[w];
        block_sums[bid] = t;
    }
}

// Final deterministic reduction over 512 block partials; out = sum / (G*NA)
__global__ void nlcl_reduce(const float* __restrict__ block_sums,
                            float* __restrict__ out)
{
    __shared__ float r[8];
    const int tid = threadIdx.x;   // 512 threads
    float v = block_sums[tid];
    v += __shfl_xor(v, 1);
    v += __shfl_xor(v, 2);
    v += __shfl_xor(v, 4);
    v += __shfl_xor(v, 8);
    v += __shfl_xor(v, 16);
    v += __shfl_xor(v, 32);
    if ((tid & 63) == 0) r[tid >> 6] = v;
    __syncthreads();
    if (tid == 0) {
        float t = 0.f;
        #pragma unroll
        for (int w = 0; w < 8; ++w) t += r[w];
        out[0] = t * (1.0f / ((float)G_NUM * (float)NAUG));
    }
}

extern "C" void kernel_launch(void* const* d_in, const int* in_sizes, int n_in,
                              void* d_out, int out_size, void* d_ws, size_t ws_size,
                              hipStream_t stream) {
    (void)in_sizes; (void)n_in; (void)out_size; (void)ws_size;
    const float* student = (const float*)d_in[0];
    const float* teacher = (const float*)d_in[1];
    const int*   kept    = (const int*)d_in[2];
    float* bs  = (float*)d_ws;
    float* out = (float*)d_out;

    nlcl_main<<<512, 512, 0, stream>>>(student, teacher, kept, bs);
    nlcl_reduce<<<1, 512, 0, stream>>>(bs, out);
}